// Round 20
// baseline (63.070 us; speedup 1.0000x reference)
//
#include <hip/hip_runtime.h>
#include <stdint.h>

// x (8,3,40,128,128) f32, W (16,3,3,3,3) f32, b (16) f32.
// conv3d VALID -> softmax(C=16) -> 4x4x4 truncating maxpool -> (8,16,9,31,31).
//
// R20 = R12/R19 (63.0 us, best) + T5 s_setprio around the MFMA clusters.
// Regime check: main loop is barrier-free (single __syncthreads after
// staging), ~15 resident waves/CU drift across tile phases -> wave role
// diversity exists (the attn-like regime where T5 measured +4-7%, m191;
// null only in barrier-lockstep loops, m190). Everything else byte-identical.

typedef float f4  __attribute__((ext_vector_type(4)));
typedef short s8v __attribute__((ext_vector_type(8)));
typedef unsigned int u2v __attribute__((ext_vector_type(2), aligned(4)));

#define LOG2E 1.44269504088896340736f

__device__ __host__ inline uint32_t bf16rnd(float x) {
    uint32_t u = __float_as_uint(x);
    return (u + 0x7FFFu + ((u >> 16) & 1u)) >> 16;
}

// B table: 4 MFMAs x 64 lanes x 4 dwords. B[col = lane&15 = oc][k=(g,r,half)]
// plane p = 8m + 2g + (r>>1):
//   r even: {w[kw0] | w[kw1]<<16};  r odd: {0 | w[kw2]<<16};  p>=27 -> 0.
// Validated R9-R19 (absmax 1.95e-3).
__global__ void build_bfrag(const float* __restrict__ W, uint32_t* __restrict__ wd) {
    int idx = blockIdx.x * 256 + threadIdx.x;   // 1024 entries
    if (idx < 1024) {
        int r = idx & 3, l = (idx >> 2) & 63, m = idx >> 8;
        int g = l >> 4, n = l & 15;
        int p = 8 * m + 2 * g + (r >> 1);
        uint32_t v = 0;
        if (p < 27) {
            int ci = p / 9, kd = (p / 3) % 3, kh = p % 3;
            const float* wb = W + (((n * 3 + ci) * 3 + kd) * 3 + kh) * 3;
            if (r & 1) v = bf16rnd(wb[2] * LOG2E) << 16;
            else       v = bf16rnd(wb[0] * LOG2E) | (bf16rnd(wb[1] * LOG2E) << 16);
        }
        wd[idx] = v;
    }
}

template<int CTRL>
__device__ inline float dppror(float v) {
    return __int_as_float(__builtin_amdgcn_update_dpp(
        0, __float_as_int(v), CTRL, 0xF, 0xF, true));
}

__global__ __launch_bounds__(256, 4)
void conv_softmax_pool(const float* __restrict__ x,
                       const float* __restrict__ bias,
                       const uint32_t* __restrict__ wd,
                       float* __restrict__ out) {
    const int bid = blockIdx.x;
    const int wt  = bid & 1;            // w-tile: wo 0..15 / 16..30
    const int ho  = (bid >> 1) % 31;
    const int dpo = (bid / 62) % 9;
    const int b   = bid / 558;          // 558 = 2*31*9

    const int w0 = wt * 64;
    const int h0 = ho * 4;
    const int d0 = dpo * 4;

    __shared__ uint32_t xs[108 * 66];   // 28512 B; row = (ci*6+d)*6+h
                                        // entry[row][w] = {bf16 x[w] | bf16 x[w+1]<<16}

    const int tid = threadIdx.x;

    // ---- stage: 3564 pair-writes across 256 threads, incremental indexing ----
    const size_t xbase = (size_t)b * (3ull * 40 * 128 * 128);
    {
        int pw  = tid % 33;              // once
        int row = tid / 33;              // once; row = (ci*6+d)*6+h
        #pragma unroll 1
        for (int it = 0; it < 14; ++it) {
            if (row < 108) {
                int h   = row % 6;
                int d   = (row / 6) % 6;
                int ci  = row / 36;
                int gw = w0 + 2 * pw;
                if (gw > 124) gw = 124;  // extras feed discarded cols only
                const float* xp = x + xbase + ((size_t)ci * 40 + (d0 + d)) * 16384
                                            + (size_t)(h0 + h) * 128 + gw;
                float2 v01 = *(const float2*)xp;
                float  v2  = xp[2];
                uint2 pr;
                asm("v_cvt_pk_bf16_f32 %0, %1, %2" : "=v"(pr.x) : "v"(v01.x), "v"(v01.y));
                asm("v_cvt_pk_bf16_f32 %0, %1, %2" : "=v"(pr.y) : "v"(v01.y), "v"(v2));
                *(uint2*)&xs[row * 66 + 2 * pw] = pr;
            }
            pw += 25; row += 7;          // += 256 in (row,pw) space (256 = 7*33+25)
            if (pw >= 33) { pw -= 33; row += 1; }
        }
    }

    const int lane = tid & 63;
    const int wv   = tid >> 6;          // wave: w positions [16wv, 16wv+16)
    const int nn   = lane & 15;         // A-row = position; D-col = oc
    const int g    = lane >> 4;

    // weight B-fragments (4 MFMAs)
    s8v bS[4];
    {
        const uint4* wsp = (const uint4*)wd;
        #pragma unroll
        for (int m = 0; m < 4; ++m)
            bS[m] = __builtin_bit_cast(s8v, wsp[m * 64 + lane]);
    }
    // per-lane static plane dword-offsets (2 planes per MFMA; clamp -> B is 0)
    uint32_t pA[4], pB[4];
    #pragma unroll
    for (int m = 0; m < 4; ++m) {
        int pa = 8 * m + 2 * g;     if (pa > 26) pa = 26;
        int pb = 8 * m + 2 * g + 1; if (pb > 26) pb = 26;
        pA[m] = (uint32_t)((pa / 9 * 6 + (pa / 3) % 3) * 6 + pa % 3) * 66u;
        pB[m] = (uint32_t)((pb / 9 * 6 + (pb / 3) % 3) * 6 + pb % 3) * 66u;
    }
    const uint32_t base0 = (uint32_t)(16 * wv + nn);
    const float bl = bias[nn] * LOG2E;

    __syncthreads();

    float pool = 0.0f;
    #pragma unroll 1
    for (int dd = 0; dd < 4; ++dd) {
        #pragma unroll 1
        for (int hh2 = 0; hh2 < 4; hh2 += 2) {
            const uint32_t tb0 = base0 + (uint32_t)((dd * 6 + hh2) * 66);
            const uint32_t tb1 = tb0 + 66u;

            f4 acc0 = {bl, bl, bl, bl};
            f4 acc1 = {bl, bl, bl, bl};
            __builtin_amdgcn_s_setprio(1);   // favor MFMA-feeding waves (T5)
            #pragma unroll
            for (int m = 0; m < 4; ++m) {
                u2v ra = *(const u2v*)&xs[tb0 + pA[m]];   // ds_read2_b32
                u2v rb = *(const u2v*)&xs[tb0 + pB[m]];
                union { uint32_t u[4]; s8v s; } A;
                A.u[0] = ra.x; A.u[1] = ra.y; A.u[2] = rb.x; A.u[3] = rb.y;
                acc0 = __builtin_amdgcn_mfma_f32_16x16x32_bf16(A.s, bS[m], acc0, 0, 0, 0);
            }
            #pragma unroll
            for (int m = 0; m < 4; ++m) {
                u2v ra = *(const u2v*)&xs[tb1 + pA[m]];
                u2v rb = *(const u2v*)&xs[tb1 + pB[m]];
                union { uint32_t u[4]; s8v s; } A;
                A.u[0] = ra.x; A.u[1] = ra.y; A.u[2] = rb.x; A.u[3] = rb.y;
                acc1 = __builtin_amdgcn_mfma_f32_16x16x32_bf16(A.s, bS[m], acc1, 0, 0, 0);
            }
            __builtin_amdgcn_s_setprio(0);

            // 8 exp2 (|arg| < ~9, raw exp2 safe)
            float e00 = __builtin_amdgcn_exp2f(acc0[0]);
            float e01 = __builtin_amdgcn_exp2f(acc0[1]);
            float e02 = __builtin_amdgcn_exp2f(acc0[2]);
            float e03 = __builtin_amdgcn_exp2f(acc0[3]);
            float e10 = __builtin_amdgcn_exp2f(acc1[0]);
            float e11 = __builtin_amdgcn_exp2f(acc1[1]);
            float e12 = __builtin_amdgcn_exp2f(acc1[2]);
            float e13 = __builtin_amdgcn_exp2f(acc1[3]);

            // 8 independent 16-lane butterflies, interleaved stage-by-stage
            float s00 = e00, s01 = e01, s02 = e02, s03 = e03;
            float s10 = e10, s11 = e11, s12 = e12, s13 = e13;
            s00 += dppror<0x121>(s00); s01 += dppror<0x121>(s01);
            s02 += dppror<0x121>(s02); s03 += dppror<0x121>(s03);
            s10 += dppror<0x121>(s10); s11 += dppror<0x121>(s11);
            s12 += dppror<0x121>(s12); s13 += dppror<0x121>(s13);
            s00 += dppror<0x122>(s00); s01 += dppror<0x122>(s01);
            s02 += dppror<0x122>(s02); s03 += dppror<0x122>(s03);
            s10 += dppror<0x122>(s10); s11 += dppror<0x122>(s11);
            s12 += dppror<0x122>(s12); s13 += dppror<0x122>(s13);
            s00 += dppror<0x124>(s00); s01 += dppror<0x124>(s01);
            s02 += dppror<0x124>(s02); s03 += dppror<0x124>(s03);
            s10 += dppror<0x124>(s10); s11 += dppror<0x124>(s11);
            s12 += dppror<0x124>(s12); s13 += dppror<0x124>(s13);
            s00 += dppror<0x128>(s00); s01 += dppror<0x128>(s01);
            s02 += dppror<0x128>(s02); s03 += dppror<0x128>(s03);
            s10 += dppror<0x128>(s10); s11 += dppror<0x128>(s11);
            s12 += dppror<0x128>(s12); s13 += dppror<0x128>(s13);

            float p00 = e00 * __builtin_amdgcn_rcpf(s00);
            float p01 = e01 * __builtin_amdgcn_rcpf(s01);
            float p02 = e02 * __builtin_amdgcn_rcpf(s02);
            float p03 = e03 * __builtin_amdgcn_rcpf(s03);
            float p10 = e10 * __builtin_amdgcn_rcpf(s10);
            float p11 = e11 * __builtin_amdgcn_rcpf(s11);
            float p12 = e12 * __builtin_amdgcn_rcpf(s12);
            float p13 = e13 * __builtin_amdgcn_rcpf(s13);

            pool = fmaxf(pool, fmaxf(fmaxf(p00, p01), fmaxf(p02, p03)));
            pool = fmaxf(pool, fmaxf(fmaxf(p10, p11), fmaxf(p12, p13)));
        }
    }

    // lane holds pooled value for (oc = nn, w-cell = g)
    {
        int wo = wt * 16 + wv * 4 + g;
        if (wo < 31)
            out[(((size_t)b * 16 + nn) * 9 + dpo) * 961
                + (size_t)ho * 31 + wo] = pool;
    }
}

extern "C" void kernel_launch(void* const* d_in, const int* in_sizes, int n_in,
                              void* d_out, int out_size, void* d_ws, size_t ws_size,
                              hipStream_t stream) {
    const float* x  = (const float*)d_in[0];
    const float* W  = (const float*)d_in[1];
    const float* bb = (const float*)d_in[2];
    float* out = (float*)d_out;

    hipLaunchKernelGGL(build_bfrag, dim3(4), dim3(256), 0, stream,
                       W, (uint32_t*)d_ws);

    const int blocks = 8 * 9 * 31 * 2;  // 4464
    hipLaunchKernelGGL(conv_softmax_pool, dim3(blocks), dim3(256), 0, stream,
                       x, bb, (const uint32_t*)d_ws, out);
}

// Round 21
// 63.001 us; speedup vs baseline: 1.0011x; 1.0011x over previous
//
#include <hip/hip_runtime.h>
#include <stdint.h>

// x (8,3,40,128,128) f32, W (16,3,3,3,3) f32, b (16) f32.
// conv3d VALID -> softmax(C=16) -> 4x4x4 truncating maxpool -> (8,16,9,31,31).
//
// R21 = R12/R19 (63.0 us champion) + LDS row stride 66 -> 68 (ROWD).
// Mechanism: 66 mod 32 = 2, so the 4 lane-groups' 16-dword gather windows
// (rows 8m+2g, row step 2 -> bank step 4) overlap -> ~4-way conflicts,
// SQ_LDS_BANK_CONFLICT = 8.0M cyc = ~21% of per-CU time. 68 mod 32 = 4 ->
// windows start at banks {o, o+8, o+16, o+24}: exact 2-way bank tiling,
// which is free (m136). One constant changed; LDS 28.5 -> 29.4 KB (still
// 5 blocks/CU).

typedef float f4  __attribute__((ext_vector_type(4)));
typedef short s8v __attribute__((ext_vector_type(8)));
typedef unsigned int u2v __attribute__((ext_vector_type(2), aligned(4)));

#define LOG2E 1.44269504088896340736f
#define ROWD 68u                        // padded dwords per (ci,d,h) row

__device__ __host__ inline uint32_t bf16rnd(float x) {
    uint32_t u = __float_as_uint(x);
    return (u + 0x7FFFu + ((u >> 16) & 1u)) >> 16;
}

// B table: 4 MFMAs x 64 lanes x 4 dwords. B[col = lane&15 = oc][k=(g,r,half)]
// plane p = 8m + 2g + (r>>1):
//   r even: {w[kw0] | w[kw1]<<16};  r odd: {0 | w[kw2]<<16};  p>=27 -> 0.
// Validated R9-R20 (absmax 1.95e-3).
__global__ void build_bfrag(const float* __restrict__ W, uint32_t* __restrict__ wd) {
    int idx = blockIdx.x * 256 + threadIdx.x;   // 1024 entries
    if (idx < 1024) {
        int r = idx & 3, l = (idx >> 2) & 63, m = idx >> 8;
        int g = l >> 4, n = l & 15;
        int p = 8 * m + 2 * g + (r >> 1);
        uint32_t v = 0;
        if (p < 27) {
            int ci = p / 9, kd = (p / 3) % 3, kh = p % 3;
            const float* wb = W + (((n * 3 + ci) * 3 + kd) * 3 + kh) * 3;
            if (r & 1) v = bf16rnd(wb[2] * LOG2E) << 16;
            else       v = bf16rnd(wb[0] * LOG2E) | (bf16rnd(wb[1] * LOG2E) << 16);
        }
        wd[idx] = v;
    }
}

template<int CTRL>
__device__ inline float dppror(float v) {
    return __int_as_float(__builtin_amdgcn_update_dpp(
        0, __float_as_int(v), CTRL, 0xF, 0xF, true));
}

__global__ __launch_bounds__(256, 4)
void conv_softmax_pool(const float* __restrict__ x,
                       const float* __restrict__ bias,
                       const uint32_t* __restrict__ wd,
                       float* __restrict__ out) {
    const int bid = blockIdx.x;
    const int wt  = bid & 1;            // w-tile: wo 0..15 / 16..30
    const int ho  = (bid >> 1) % 31;
    const int dpo = (bid / 62) % 9;
    const int b   = bid / 558;          // 558 = 2*31*9

    const int w0 = wt * 64;
    const int h0 = ho * 4;
    const int d0 = dpo * 4;

    __shared__ uint32_t xs[108 * ROWD]; // 29376 B; row = (ci*6+d)*6+h
                                        // entry[row][w] = {bf16 x[w] | bf16 x[w+1]<<16}

    const int tid = threadIdx.x;

    // ---- stage: 3564 pair-writes across 256 threads, incremental indexing ----
    const size_t xbase = (size_t)b * (3ull * 40 * 128 * 128);
    {
        int pw  = tid % 33;              // once
        int row = tid / 33;              // once; row = (ci*6+d)*6+h
        #pragma unroll 1
        for (int it = 0; it < 14; ++it) {
            if (row < 108) {
                int h   = row % 6;
                int d   = (row / 6) % 6;
                int ci  = row / 36;
                int gw = w0 + 2 * pw;
                if (gw > 124) gw = 124;  // extras feed discarded cols only
                const float* xp = x + xbase + ((size_t)ci * 40 + (d0 + d)) * 16384
                                            + (size_t)(h0 + h) * 128 + gw;
                float2 v01 = *(const float2*)xp;
                float  v2  = xp[2];
                uint2 pr;
                asm("v_cvt_pk_bf16_f32 %0, %1, %2" : "=v"(pr.x) : "v"(v01.x), "v"(v01.y));
                asm("v_cvt_pk_bf16_f32 %0, %1, %2" : "=v"(pr.y) : "v"(v01.y), "v"(v2));
                *(uint2*)&xs[(uint32_t)row * ROWD + 2 * pw] = pr;
            }
            pw += 25; row += 7;          // += 256 in (row,pw) space (256 = 7*33+25)
            if (pw >= 33) { pw -= 33; row += 1; }
        }
    }

    const int lane = tid & 63;
    const int wv   = tid >> 6;          // wave: w positions [16wv, 16wv+16)
    const int nn   = lane & 15;         // A-row = position; D-col = oc
    const int g    = lane >> 4;

    // weight B-fragments (4 MFMAs)
    s8v bS[4];
    {
        const uint4* wsp = (const uint4*)wd;
        #pragma unroll
        for (int m = 0; m < 4; ++m)
            bS[m] = __builtin_bit_cast(s8v, wsp[m * 64 + lane]);
    }
    // per-lane static plane dword-offsets (2 planes per MFMA; clamp -> B is 0)
    uint32_t pA[4], pB[4];
    #pragma unroll
    for (int m = 0; m < 4; ++m) {
        int pa = 8 * m + 2 * g;     if (pa > 26) pa = 26;
        int pb = 8 * m + 2 * g + 1; if (pb > 26) pb = 26;
        pA[m] = (uint32_t)((pa / 9 * 6 + (pa / 3) % 3) * 6 + pa % 3) * ROWD;
        pB[m] = (uint32_t)((pb / 9 * 6 + (pb / 3) % 3) * 6 + pb % 3) * ROWD;
    }
    const uint32_t base0 = (uint32_t)(16 * wv + nn);
    const float bl = bias[nn] * LOG2E;

    __syncthreads();

    float pool = 0.0f;
    #pragma unroll 1
    for (int dd = 0; dd < 4; ++dd) {
        #pragma unroll 1
        for (int hh2 = 0; hh2 < 4; hh2 += 2) {
            const uint32_t tb0 = base0 + (uint32_t)(dd * 6 + hh2) * ROWD;
            const uint32_t tb1 = tb0 + ROWD;

            f4 acc0 = {bl, bl, bl, bl};
            f4 acc1 = {bl, bl, bl, bl};
            #pragma unroll
            for (int m = 0; m < 4; ++m) {
                u2v ra = *(const u2v*)&xs[tb0 + pA[m]];   // ds_read2_b32
                u2v rb = *(const u2v*)&xs[tb0 + pB[m]];
                union { uint32_t u[4]; s8v s; } A;
                A.u[0] = ra.x; A.u[1] = ra.y; A.u[2] = rb.x; A.u[3] = rb.y;
                acc0 = __builtin_amdgcn_mfma_f32_16x16x32_bf16(A.s, bS[m], acc0, 0, 0, 0);
            }
            #pragma unroll
            for (int m = 0; m < 4; ++m) {
                u2v ra = *(const u2v*)&xs[tb1 + pA[m]];
                u2v rb = *(const u2v*)&xs[tb1 + pB[m]];
                union { uint32_t u[4]; s8v s; } A;
                A.u[0] = ra.x; A.u[1] = ra.y; A.u[2] = rb.x; A.u[3] = rb.y;
                acc1 = __builtin_amdgcn_mfma_f32_16x16x32_bf16(A.s, bS[m], acc1, 0, 0, 0);
            }

            // 8 exp2 (|arg| < ~9, raw exp2 safe)
            float e00 = __builtin_amdgcn_exp2f(acc0[0]);
            float e01 = __builtin_amdgcn_exp2f(acc0[1]);
            float e02 = __builtin_amdgcn_exp2f(acc0[2]);
            float e03 = __builtin_amdgcn_exp2f(acc0[3]);
            float e10 = __builtin_amdgcn_exp2f(acc1[0]);
            float e11 = __builtin_amdgcn_exp2f(acc1[1]);
            float e12 = __builtin_amdgcn_exp2f(acc1[2]);
            float e13 = __builtin_amdgcn_exp2f(acc1[3]);

            // 8 independent 16-lane butterflies, interleaved stage-by-stage
            float s00 = e00, s01 = e01, s02 = e02, s03 = e03;
            float s10 = e10, s11 = e11, s12 = e12, s13 = e13;
            s00 += dppror<0x121>(s00); s01 += dppror<0x121>(s01);
            s02 += dppror<0x121>(s02); s03 += dppror<0x121>(s03);
            s10 += dppror<0x121>(s10); s11 += dppror<0x121>(s11);
            s12 += dppror<0x121>(s12); s13 += dppror<0x121>(s13);
            s00 += dppror<0x122>(s00); s01 += dppror<0x122>(s01);
            s02 += dppror<0x122>(s02); s03 += dppror<0x122>(s03);
            s10 += dppror<0x122>(s10); s11 += dppror<0x122>(s11);
            s12 += dppror<0x122>(s12); s13 += dppror<0x122>(s13);
            s00 += dppror<0x124>(s00); s01 += dppror<0x124>(s01);
            s02 += dppror<0x124>(s02); s03 += dppror<0x124>(s03);
            s10 += dppror<0x124>(s10); s11 += dppror<0x124>(s11);
            s12 += dppror<0x124>(s12); s13 += dppror<0x124>(s13);
            s00 += dppror<0x128>(s00); s01 += dppror<0x128>(s01);
            s02 += dppror<0x128>(s02); s03 += dppror<0x128>(s03);
            s10 += dppror<0x128>(s10); s11 += dppror<0x128>(s11);
            s12 += dppror<0x128>(s12); s13 += dppror<0x128>(s13);

            float p00 = e00 * __builtin_amdgcn_rcpf(s00);
            float p01 = e01 * __builtin_amdgcn_rcpf(s01);
            float p02 = e02 * __builtin_amdgcn_rcpf(s02);
            float p03 = e03 * __builtin_amdgcn_rcpf(s03);
            float p10 = e10 * __builtin_amdgcn_rcpf(s10);
            float p11 = e11 * __builtin_amdgcn_rcpf(s11);
            float p12 = e12 * __builtin_amdgcn_rcpf(s12);
            float p13 = e13 * __builtin_amdgcn_rcpf(s13);

            pool = fmaxf(pool, fmaxf(fmaxf(p00, p01), fmaxf(p02, p03)));
            pool = fmaxf(pool, fmaxf(fmaxf(p10, p11), fmaxf(p12, p13)));
        }
    }

    // lane holds pooled value for (oc = nn, w-cell = g)
    {
        int wo = wt * 16 + wv * 4 + g;
        if (wo < 31)
            out[(((size_t)b * 16 + nn) * 9 + dpo) * 961
                + (size_t)ho * 31 + wo] = pool;
    }
}

extern "C" void kernel_launch(void* const* d_in, const int* in_sizes, int n_in,
                              void* d_out, int out_size, void* d_ws, size_t ws_size,
                              hipStream_t stream) {
    const float* x  = (const float*)d_in[0];
    const float* W  = (const float*)d_in[1];
    const float* bb = (const float*)d_in[2];
    float* out = (float*)d_out;

    hipLaunchKernelGGL(build_bfrag, dim3(4), dim3(256), 0, stream,
                       W, (uint32_t*)d_ws);

    const int blocks = 8 * 9 * 31 * 2;  // 4464
    hipLaunchKernelGGL(conv_softmax_pool, dim3(blocks), dim3(256), 0, stream,
                       x, bb, (const uint32_t*)d_ws, out);
}